// Round 3
// baseline (307.341 us; speedup 1.0000x reference)
//
#include <hip/hip_runtime.h>
#include <hip/hip_bf16.h>

typedef __attribute__((ext_vector_type(8))) short short8;
typedef __attribute__((ext_vector_type(4))) float f32x4;
typedef __attribute__((ext_vector_type(4))) unsigned short ushort4n;

#define NP_TOTAL 196608   // (1024*16) * 12 positions
#define MT 32             // positions per tile
#define BLK 256
#define GRID 768          // 3 blocks/CU, one generation
#define TILES_PER_BLK 8   // 768*8 = 6144 tiles

// LDS layout (byte offsets). Tiles row-swizzled: byte ^= ((row&7)<<4)
#define A1_OFF   0        // 32 rows x 1024B (512 bf16/row) = 32768
#define A2_OFF   0        // 32 rows x 128B  (aliases A1)   =  4096
#define A3_OFF   4096     // 32 rows x 128B  (aliases A1)   =  4096
#define PART_OFF 32768    // 32 rows x 128B  (32 fp32/row)  =  4096
#define SMEM_BYTES 36864

// workspace layout (bytes)
#define WS_B1F   0        // float[64]
#define WS_B2F   256      // float[32]
#define WS_W1F   512      // bf16[32768] frag-ordered
#define WS_W2F   66048    // bf16[2048]  frag-ordered
#define WS_W3F   70144    // bf16[1024]  frag-ordered
#define WS_EL    73728    // float2[256000] interleaved (cat_emb, cat_lin)

__global__ void prep_kernel(
    const float* __restrict__ w1, const float* __restrict__ b1,
    const float* __restrict__ g1, const float* __restrict__ bt1,
    const float* __restrict__ m1, const float* __restrict__ v1,
    const float* __restrict__ w2, const float* __restrict__ b2,
    const float* __restrict__ g2, const float* __restrict__ bt2,
    const float* __restrict__ m2, const float* __restrict__ v2,
    const float* __restrict__ w3,
    const float* __restrict__ cat_emb, const float* __restrict__ cat_lin,
    float* __restrict__ bias1f, float* __restrict__ bias2f,
    __hip_bfloat16* __restrict__ W1f, __hip_bfloat16* __restrict__ W2f,
    __hip_bfloat16* __restrict__ W3f, float2* __restrict__ EL)
{
    int t  = blockIdx.x * blockDim.x + threadIdx.x;
    int nt = gridDim.x * blockDim.x;
    if (t < 64)            { float s = g1[t] / sqrtf(v1[t] + 1e-5f); bias1f[t] = (b1[t] - m1[t]) * s + bt1[t]; }
    if (t >= 64 && t < 96) { int o = t - 64; float s = g2[o] / sqrtf(v2[o] + 1e-5f); bias2f[o] = (b2[o] - m2[o]) * s + bt2[o]; }
    for (int i = t; i < 8 * 1000 * 32; i += nt) {
        float2 v; v.x = cat_emb[i]; v.y = cat_lin[i];
        EL[i] = v;
    }
    // W1 frag order: [ct(4)][kk(16)][lane(64)][j(8)], B[k][n] = s1[n]*w1[n][k]
    for (int fi = t; fi < 64 * 512; fi += nt) {
        int j = fi & 7, lane = (fi >> 3) & 63, kt = fi >> 9;
        int ct = kt >> 4, kk = kt & 15;
        int k = kk * 32 + ((lane >> 4) << 3) + j;
        int n = ct * 16 + (lane & 15);
        float s = g1[n] / sqrtf(v1[n] + 1e-5f);
        W1f[fi] = __float2bfloat16(s * w1[n * 512 + k]);
    }
    // W2 frag order: [ct(2)][kk(2)][lane][j]
    for (int fi = t; fi < 2048; fi += nt) {
        int j = fi & 7, lane = (fi >> 3) & 63, kt = fi >> 9;
        int ct = kt >> 1, kk = kt & 1;
        int k = kk * 32 + ((lane >> 4) << 3) + j;
        int n = ct * 16 + (lane & 15);
        float s = g2[n] / sqrtf(v2[n] + 1e-5f);
        W2f[fi] = __float2bfloat16(s * w2[n * 64 + k]);
    }
    // W3 frag order: [ct(2)][lane][j]
    for (int fi = t; fi < 1024; fi += nt) {
        int j = fi & 7, lane = (fi >> 3) & 63, ct = fi >> 9;
        int k = ((lane >> 4) << 3) + j;
        int n = ct * 16 + (lane & 15);
        W3f[fi] = __float2bfloat16(w3[n * 32 + k]);
    }
}

static __device__ __forceinline__ unsigned short bf16bits(float f) {
    __hip_bfloat16 h = __float2bfloat16(f);
    return *(unsigned short*)&h;
}

__global__ __launch_bounds__(BLK, 3) void fused_kernel(
    const float* __restrict__ x,
    const float* __restrict__ cont_w,  const float* __restrict__ cont_b,
    const float* __restrict__ cont_lw, const float* __restrict__ cont_lb,
    const float* __restrict__ fin_bias,
    const float* __restrict__ bias1f,  const float* __restrict__ bias2f,
    const float* __restrict__ out_b,
    const __hip_bfloat16* __restrict__ W1f,
    const __hip_bfloat16* __restrict__ W2f,
    const __hip_bfloat16* __restrict__ W3f,
    const float2* __restrict__ EL,
    float* __restrict__ out)
{
    __shared__ __align__(16) char smem[SMEM_BYTES];
    const int tid  = threadIdx.x;
    const int lane = tid & 63;
    const int wv   = tid >> 6;

    // ---- weight-stationary: load all W fragments ONCE ----
    const short8* W1v = (const short8*)W1f;
    short8 w1r[16];
    #pragma unroll
    for (int kk = 0; kk < 16; ++kk) w1r[kk] = W1v[(wv * 16 + kk) * 64 + lane];

    const int rt2 = wv >> 1, ct2 = wv & 1;       // also used for GEMM3
    const short8* W2v = (const short8*)W2f;
    short8 w2r0 = W2v[(ct2 * 2 + 0) * 64 + lane];
    short8 w2r1 = W2v[(ct2 * 2 + 1) * 64 + lane];
    const short8* W3v = (const short8*)W3f;
    short8 w3r = W3v[ct2 * 64 + lane];

    const float bo1 = bias1f[wv * 16 + (lane & 15)];
    const float bo2 = bias2f[ct2 * 16 + (lane & 15)];
    const float ob  = out_b[ct2 * 16 + (lane & 15)];

    const int p  = tid >> 3;            // position 0..31
    const int d0 = (tid & 7) << 2;      // d group
    const int swzp = (p & 7) << 4;
    const float4 finb = *(const float4*)(fin_bias + d0);
    const int akb = (lane >> 4) << 3;   // k sub-offset within fragment

    for (int it = 0; it < TILES_PER_BLK; ++it) {
        const int tile = blockIdx.x * TILES_PER_BLK + it;

        // ---- Phase A: embeddings, FM + linear (fp32), A1 tile (bf16) ----
        {
            const float* xp = x + (size_t)tile * (MT * 16) + p * 16;
            float4 xi0 = *(const float4*)(xp);
            float4 xi1 = *(const float4*)(xp + 4);
            float4 xc0 = *(const float4*)(xp + 8);
            float4 xc1 = *(const float4*)(xp + 12);
            float idxf[8] = {xi0.x, xi0.y, xi0.z, xi0.w, xi1.x, xi1.y, xi1.z, xi1.w};
            float cf[8]   = {xc0.x, xc0.y, xc0.z, xc0.w, xc1.x, xc1.y, xc1.z, xc1.w};

            float4 ssum = {0.f, 0.f, 0.f, 0.f}, ssq = {0.f, 0.f, 0.f, 0.f};
            float4 lin = finb;
            char* arow = smem + A1_OFF + p * 1024;

            #pragma unroll
            for (int f = 0; f < 8; ++f) {
                int ix = (int)idxf[f];
                const float4* src = (const float4*)(EL + ((f * 1000 + ix) * 32 + d0));
                float4 v0 = src[0];
                float4 v1 = src[1];
                float4 e  = {v0.x, v0.z, v1.x, v1.z};
                float4 el = {v0.y, v0.w, v1.y, v1.w};
                ssum += e; ssq += e * e; lin += el;
                ushort4n ev = {bf16bits(e.x), bf16bits(e.y), bf16bits(e.z), bf16bits(e.w)};
                *(ushort4n*)(arow + (((f * 32 + d0) * 2) ^ swzp)) = ev;
            }
            #pragma unroll
            for (int f = 0; f < 8; ++f) {
                float c  = cf[f];
                float4 w  = *(const float4*)(cont_w  + f * 32 + d0);
                float4 b  = *(const float4*)(cont_b  + f * 32 + d0);
                float4 lw = *(const float4*)(cont_lw + f * 32 + d0);
                float4 lb = *(const float4*)(cont_lb + f * 32 + d0);
                float4 e, el;
                e.x = fmaf(c, w.x, b.x);   e.y = fmaf(c, w.y, b.y);
                e.z = fmaf(c, w.z, b.z);   e.w = fmaf(c, w.w, b.w);
                el.x = fmaf(c, lw.x, lb.x); el.y = fmaf(c, lw.y, lb.y);
                el.z = fmaf(c, lw.z, lb.z); el.w = fmaf(c, lw.w, lb.w);
                ssum += e; ssq += e * e; lin += el;
                ushort4n ev = {bf16bits(e.x), bf16bits(e.y), bf16bits(e.z), bf16bits(e.w)};
                *(ushort4n*)(arow + ((((8 + f) * 32 + d0) * 2) ^ swzp)) = ev;
            }
            float4 part;
            part.x = lin.x + 0.5f * (ssum.x * ssum.x - ssq.x);
            part.y = lin.y + 0.5f * (ssum.y * ssum.y - ssq.y);
            part.z = lin.z + 0.5f * (ssum.z * ssum.z - ssq.z);
            part.w = lin.w + 0.5f * (ssum.w * ssum.w - ssq.w);
            *(float4*)(smem + PART_OFF + ((p * 128 + d0 * 4) ^ swzp)) = part;
        }
        __syncthreads();

        // ---- GEMM1: (32 x 512) x (512 x 64); wave owns ct=wv, loops rt ----
        f32x4 acc0 = {0.f, 0.f, 0.f, 0.f}, acc1 = {0.f, 0.f, 0.f, 0.f};
        {
            const int ar0 = (lane & 15);
            const int ar1 = 16 + (lane & 15);
            #pragma unroll
            for (int kk = 0; kk < 16; ++kk) {
                short8 a0 = *(const short8*)(smem + A1_OFF + ((ar0 * 1024 + (kk * 32 + akb) * 2) ^ ((ar0 & 7) << 4)));
                acc0 = __builtin_amdgcn_mfma_f32_16x16x32_bf16(a0, w1r[kk], acc0, 0, 0, 0);
            }
            #pragma unroll
            for (int kk = 0; kk < 16; ++kk) {
                short8 a1 = *(const short8*)(smem + A1_OFF + ((ar1 * 1024 + (kk * 32 + akb) * 2) ^ ((ar1 & 7) << 4)));
                acc1 = __builtin_amdgcn_mfma_f32_16x16x32_bf16(a1, w1r[kk], acc1, 0, 0, 0);
            }
        }
        __syncthreads();   // all waves done reading A1; A2 may overwrite

        // h1 = relu(acc + bias1) -> A2 (bf16, swizzled). col = wv*16+(lane&15)
        {
            const int o = wv * 16 + (lane & 15);
            const int pb = (lane >> 4) << 2;
            #pragma unroll
            for (int r = 0; r < 4; ++r) {
                int p0 = pb + r;
                int p1 = 16 + pb + r;
                float h0 = fmaxf(acc0[r] + bo1, 0.f);
                float h1 = fmaxf(acc1[r] + bo1, 0.f);
                *(__hip_bfloat16*)(smem + A2_OFF + ((p0 * 128 + o * 2) ^ ((p0 & 7) << 4))) = __float2bfloat16(h0);
                *(__hip_bfloat16*)(smem + A2_OFF + ((p1 * 128 + o * 2) ^ ((p1 & 7) << 4))) = __float2bfloat16(h1);
            }
        }
        __syncthreads();

        // ---- GEMM2: (32 x 64) x (64 x 32); wave (rt2, ct2) ----
        f32x4 acc2 = {0.f, 0.f, 0.f, 0.f};
        {
            const int arow2 = rt2 * 16 + (lane & 15);
            short8 a0 = *(const short8*)(smem + A2_OFF + ((arow2 * 128 + akb * 2) ^ ((arow2 & 7) << 4)));
            acc2 = __builtin_amdgcn_mfma_f32_16x16x32_bf16(a0, w2r0, acc2, 0, 0, 0);
            short8 a1 = *(const short8*)(smem + A2_OFF + ((arow2 * 128 + (32 + akb) * 2) ^ ((arow2 & 7) << 4)));
            acc2 = __builtin_amdgcn_mfma_f32_16x16x32_bf16(a1, w2r1, acc2, 0, 0, 0);
        }
        // h2 -> A3
        {
            const int o = ct2 * 16 + (lane & 15);
            const int pb = rt2 * 16 + ((lane >> 4) << 2);
            #pragma unroll
            for (int r = 0; r < 4; ++r) {
                int pp = pb + r;
                float h = fmaxf(acc2[r] + bo2, 0.f);
                *(__hip_bfloat16*)(smem + A3_OFF + ((pp * 128 + o * 2) ^ ((pp & 7) << 4))) = __float2bfloat16(h);
            }
        }
        __syncthreads();

        // ---- GEMM3: (32 x 32) x (32 x 32) + epilogue ----
        {
            const int arow3 = rt2 * 16 + (lane & 15);
            short8 a3 = *(const short8*)(smem + A3_OFF + ((arow3 * 128 + akb * 2) ^ ((arow3 & 7) << 4)));
            f32x4 z = {0.f, 0.f, 0.f, 0.f};
            f32x4 acc3 = __builtin_amdgcn_mfma_f32_16x16x32_bf16(a3, w3r, z, 0, 0, 0);

            const int dcol = ct2 * 16 + (lane & 15);
            const int pb = rt2 * 16 + ((lane >> 4) << 2);
            size_t outbase = (size_t)tile * (MT * 32);
            #pragma unroll
            for (int r = 0; r < 4; ++r) {
                int pp = pb + r;
                float part = *(const float*)(smem + PART_OFF + ((pp * 128 + dcol * 4) ^ ((pp & 7) << 4)));
                out[outbase + pp * 32 + dcol] = part + ob + acc3[r];
            }
        }
        __syncthreads();   // protect A1/PART rewrite by next tile's Phase A
    }
}

extern "C" void kernel_launch(void* const* d_in, const int* in_sizes, int n_in,
                              void* d_out, int out_size, void* d_ws, size_t ws_size,
                              hipStream_t stream) {
    const float* x        = (const float*)d_in[0];
    const float* cat_emb  = (const float*)d_in[1];
    const float* cat_lin  = (const float*)d_in[2];
    const float* cont_w   = (const float*)d_in[3];
    const float* cont_b   = (const float*)d_in[4];
    const float* cont_lw  = (const float*)d_in[5];
    const float* cont_lb  = (const float*)d_in[6];
    const float* fin_bias = (const float*)d_in[7];
    const float* dnn1_w   = (const float*)d_in[8];
    const float* dnn1_b   = (const float*)d_in[9];
    const float* bn1_g    = (const float*)d_in[10];
    const float* bn1_bt   = (const float*)d_in[11];
    const float* bn1_m    = (const float*)d_in[12];
    const float* bn1_v    = (const float*)d_in[13];
    const float* dnn2_w   = (const float*)d_in[14];
    const float* dnn2_b   = (const float*)d_in[15];
    const float* bn2_g    = (const float*)d_in[16];
    const float* bn2_bt   = (const float*)d_in[17];
    const float* bn2_m    = (const float*)d_in[18];
    const float* bn2_v    = (const float*)d_in[19];
    const float* out_w    = (const float*)d_in[20];
    const float* out_b    = (const float*)d_in[21];

    char* ws = (char*)d_ws;
    float* bias1f = (float*)(ws + WS_B1F);
    float* bias2f = (float*)(ws + WS_B2F);
    __hip_bfloat16* W1f = (__hip_bfloat16*)(ws + WS_W1F);
    __hip_bfloat16* W2f = (__hip_bfloat16*)(ws + WS_W2F);
    __hip_bfloat16* W3f = (__hip_bfloat16*)(ws + WS_W3F);
    float2* EL = (float2*)(ws + WS_EL);

    hipLaunchKernelGGL(prep_kernel, dim3(256), dim3(BLK), 0, stream,
                       dnn1_w, dnn1_b, bn1_g, bn1_bt, bn1_m, bn1_v,
                       dnn2_w, dnn2_b, bn2_g, bn2_bt, bn2_m, bn2_v,
                       out_w, cat_emb, cat_lin, bias1f, bias2f, W1f, W2f, W3f, EL);

    hipLaunchKernelGGL(fused_kernel, dim3(GRID), dim3(BLK), 0, stream,
                       x, cont_w, cont_b, cont_lw, cont_lb,
                       fin_bias, bias1f, bias2f, out_b, W1f, W2f, W3f, EL,
                       (float*)d_out);
}

// Round 4
// 52.182 us; speedup vs baseline: 5.8898x; 5.8898x over previous
//
#include <hip/hip_runtime.h>
#include <hip/hip_bf16.h>

typedef __attribute__((ext_vector_type(8))) short short8;
typedef __attribute__((ext_vector_type(4))) float f32x4;
typedef __attribute__((ext_vector_type(4))) unsigned short ushort4n;

#define BLK 256
#define NTILES 6144       // 196608 positions / 32 per tile

// ---- LDS layout (byte offsets) ----
// A1: MFMA A-fragment-native: [kk(9)][rt(2)] chunks of 1024B (64 lanes x 16B)
#define A1_OFF   0        // 18432 B
#define A2_OFF   0        // [kk(2)][rt(2)]x1024 = 4096 (aliases A1 after GEMM1)
#define A3_OFF   4096     // [rt(2)]x1024 = 2048 (aliases A1)
#define FMC_OFF  18432    // 32 rows x 66 dwords (float2 per d: ssum,Gcont) = 8448
#define XS_OFF   18432    // x stage 32x64B = 2048 (aliases FMC; dead before FMC write)
#define PART_OFF 26880    // G_cat: 32 x 32 fp32 = 4096
#define SMEM_BYTES 30976  // -> 5 blocks/CU

// ---- workspace layout (bytes) ----
#define WS_B1F 0          // float[64]
#define WS_B2F 256        // float[32]
#define WS_W1F 512        // bf16 [ct(8)][kk(9)][lane(64)][j(8)] = 36864 el = 73728 B
#define WS_W2F 74240      // bf16 [ct(2)][kk(2)][lane][j] = 2048 el = 4096 B
#define WS_W3F 78336      // bf16 [ct(2)][lane][j] = 1024 el = 2048 B
#define WS_EL  81920      // float2[256000] interleaved (cat_emb, cat_lin) = 2048000 B

__global__ void prep_kernel(
    const float* __restrict__ w1, const float* __restrict__ b1,
    const float* __restrict__ g1, const float* __restrict__ bt1,
    const float* __restrict__ m1, const float* __restrict__ v1,
    const float* __restrict__ w2, const float* __restrict__ b2,
    const float* __restrict__ g2, const float* __restrict__ bt2,
    const float* __restrict__ m2, const float* __restrict__ v2,
    const float* __restrict__ w3,
    const float* __restrict__ cat_emb, const float* __restrict__ cat_lin,
    const float* __restrict__ cont_w,  const float* __restrict__ cont_b,
    const float* __restrict__ cont_lw, const float* __restrict__ cont_lb,
    const float* __restrict__ fin_bias,
    float* __restrict__ bias1f, float* __restrict__ bias2f,
    __hip_bfloat16* __restrict__ W1f, __hip_bfloat16* __restrict__ W2f,
    __hip_bfloat16* __restrict__ W3f, float2* __restrict__ EL)
{
    int t  = blockIdx.x * blockDim.x + threadIdx.x;
    int nt = gridDim.x * blockDim.x;
    if (t < 64) {
        float s = g1[t] / sqrtf(v1[t] + 1e-5f);
        float cbsum = 0.f;
        for (int f = 0; f < 8; ++f)
            for (int d = 0; d < 32; ++d)
                cbsum += w1[t * 512 + 256 + f * 32 + d] * cont_b[f * 32 + d];
        bias1f[t] = (b1[t] + cbsum - m1[t]) * s + bt1[t];
    }
    if (t >= 64 && t < 96) {
        int o = t - 64;
        float s = g2[o] / sqrtf(v2[o] + 1e-5f);
        bias2f[o] = (b2[o] - m2[o]) * s + bt2[o];
    }
    for (int i = t; i < 8 * 1000 * 32; i += nt) {
        float2 v; v.x = cat_emb[i]; v.y = cat_lin[i];
        EL[i] = v;
    }
    // Composite B for GEMM1: K=288 rows (256 cat e | 8 c | 8 c^2 | 1 | pad),
    // N=128 cols (64 h1 | 32 ssum_tot | 32 G_cont).
    for (int fi = t; fi < 8 * 9 * 512; fi += nt) {
        int j = fi & 7, lane = (fi >> 3) & 63, t2 = fi >> 9;
        int kk = t2 % 9, ct = t2 / 9;
        int k = kk * 32 + ((lane >> 4) << 3) + j;
        float val = 0.f;
        if (ct < 4) {                       // h1 cols, n = ct*16+(lane&15)
            int n = ct * 16 + (lane & 15);
            float s = g1[n] / sqrtf(v1[n] + 1e-5f);
            if (k < 256) val = s * w1[n * 512 + k];
            else if (k < 264) {             // c-row f: Wc[n,f]
                int f = k - 256; float a = 0.f;
                for (int d = 0; d < 32; ++d)
                    a += w1[n * 512 + 256 + f * 32 + d] * cont_w[f * 32 + d];
                val = s * a;
            }
        } else if (ct < 6) {                // ssum_tot cols, d = (ct-4)*16+(lane&15)
            int d = (ct - 4) * 16 + (lane & 15);
            if (k < 256) val = ((k & 31) == d) ? 1.f : 0.f;
            else if (k < 264) val = cont_w[(k - 256) * 32 + d];
            else if (k == 272) { float a = 0.f; for (int f = 0; f < 8; ++f) a += cont_b[f * 32 + d]; val = a; }
        } else {                            // G_cont cols, d = (ct-6)*16+(lane&15)
            int d = (ct - 6) * 16 + (lane & 15);
            if (k >= 256 && k < 264) {
                int f = k - 256;
                val = cont_lw[f * 32 + d] - cont_w[f * 32 + d] * cont_b[f * 32 + d];
            } else if (k >= 264 && k < 272) {
                int f = k - 264; float w = cont_w[f * 32 + d];
                val = -0.5f * w * w;
            } else if (k == 272) {
                float a = fin_bias[d];
                for (int f = 0; f < 8; ++f)
                    a += cont_lb[f * 32 + d] - 0.5f * cont_b[f * 32 + d] * cont_b[f * 32 + d];
                val = a;
            }
        }
        W1f[fi] = __float2bfloat16(val);
    }
    // W2 frag order: [ct(2)][kk(2)][lane][j]
    for (int fi = t; fi < 2048; fi += nt) {
        int j = fi & 7, lane = (fi >> 3) & 63, kt = fi >> 9;
        int ct = kt >> 1, kk = kt & 1;
        int k = kk * 32 + ((lane >> 4) << 3) + j;
        int n = ct * 16 + (lane & 15);
        float s = g2[n] / sqrtf(v2[n] + 1e-5f);
        W2f[fi] = __float2bfloat16(s * w2[n * 64 + k]);
    }
    // W3 frag order: [ct(2)][lane][j]
    for (int fi = t; fi < 1024; fi += nt) {
        int j = fi & 7, lane = (fi >> 3) & 63, ct = fi >> 9;
        int k = ((lane >> 4) << 3) + j;
        int n = ct * 16 + (lane & 15);
        W3f[fi] = __float2bfloat16(w3[n * 32 + k]);
    }
}

static __device__ __forceinline__ unsigned short bf16bits(float f) {
    __hip_bfloat16 h = __float2bfloat16(f);
    return *(unsigned short*)&h;
}

__global__ __launch_bounds__(BLK, 4) void fused_kernel(
    const float* __restrict__ x,
    const float* __restrict__ bias1f, const float* __restrict__ bias2f,
    const float* __restrict__ out_b,
    const __hip_bfloat16* __restrict__ W1f,
    const __hip_bfloat16* __restrict__ W2f,
    const __hip_bfloat16* __restrict__ W3f,
    const float2* __restrict__ EL,
    float* __restrict__ out)
{
    __shared__ __align__(16) char smem[SMEM_BYTES];
    const int tid  = threadIdx.x;
    const int lane = tid & 63;
    const int wv   = tid >> 6;
    const int tile = blockIdx.x;

    // ---- stage x (32 pos x 16 feat) ----
    if (tid < 128)
        ((float4*)(smem + XS_OFF))[tid] = ((const float4*)(x + (size_t)tile * 512))[tid];
    __syncthreads();                                        // B1

    // ---- Phase A: gathers, G_cat, A1 fragments ----
    {
        const int p = tid >> 3, d0 = (tid & 7) << 2, g = d0 >> 3, rtp = p >> 4;
        const float* xs = (const float*)(smem + XS_OFF) + p * 16;
        float4 xi0 = ((const float4*)xs)[0];
        float4 xi1 = ((const float4*)xs)[1];
        float4 xc0 = ((const float4*)xs)[2];
        float4 xc1 = ((const float4*)xs)[3];
        float idxf[8] = {xi0.x, xi0.y, xi0.z, xi0.w, xi1.x, xi1.y, xi1.z, xi1.w};
        float cf[8]   = {xc0.x, xc0.y, xc0.z, xc0.w, xc1.x, xc1.y, xc1.z, xc1.w};

        char* aw = smem + A1_OFF + rtp * 1024 + ((p & 15) + 16 * g) * 16 + (d0 & 7) * 2;
        float4 lin = {0.f, 0.f, 0.f, 0.f}, ssq = {0.f, 0.f, 0.f, 0.f};
        #pragma unroll
        for (int f = 0; f < 8; ++f) {
            int ix = (int)idxf[f];
            const float4* src = (const float4*)(EL + ((f * 1000 + ix) * 32 + d0));
            float4 v0 = src[0], v1 = src[1];
            float4 e  = {v0.x, v0.z, v1.x, v1.z};
            float4 el = {v0.y, v0.w, v1.y, v1.w};
            lin += el; ssq += e * e;
            ushort4n ev = {bf16bits(e.x), bf16bits(e.y), bf16bits(e.z), bf16bits(e.w)};
            *(ushort4n*)(aw + f * 2048) = ev;               // chunk kk=f (offset imm)
        }
        // kk=8 chunk: cols = [c(8) | c^2(8) | 1,0.. | 0..] by d0-group g
        {
            char* c8 = smem + A1_OFF + (8 * 2 + rtp) * 1024 + ((p & 15) + 16 * g) * 16;
            ushort4n lo = {0, 0, 0, 0}, hi = {0, 0, 0, 0};
            if (g == 0) {
                lo = (ushort4n){bf16bits(cf[0]), bf16bits(cf[1]), bf16bits(cf[2]), bf16bits(cf[3])};
                hi = (ushort4n){bf16bits(cf[4]), bf16bits(cf[5]), bf16bits(cf[6]), bf16bits(cf[7])};
            } else if (g == 1) {
                lo = (ushort4n){bf16bits(cf[0]*cf[0]), bf16bits(cf[1]*cf[1]), bf16bits(cf[2]*cf[2]), bf16bits(cf[3]*cf[3])};
                hi = (ushort4n){bf16bits(cf[4]*cf[4]), bf16bits(cf[5]*cf[5]), bf16bits(cf[6]*cf[6]), bf16bits(cf[7]*cf[7])};
            } else if (g == 2) {
                lo = (ushort4n){0x3F80, 0, 0, 0};           // 1.0, then zeros
            }
            *(ushort4n*)c8 = lo;
            *(ushort4n*)(c8 + 8) = hi;
        }
        float4 G = lin - 0.5f * ssq;                        // G_cat = lin_cat - 0.5*ssq_cat
        *(float4*)(smem + PART_OFF + p * 128 + d0 * 4) = G;
    }
    __syncthreads();                                        // B2

    // ---- GEMM1: (32 x 288) x (288 x 128) ----
    const short8* W1v = (const short8*)W1f;
    f32x4 ah0 = {0,0,0,0}, ah1 = {0,0,0,0}, af0 = {0,0,0,0}, af1 = {0,0,0,0};
    {
        const int cth = wv, ctf = wv + 4;
        #pragma unroll
        for (int kk = 0; kk < 9; ++kk) {
            short8 bh = W1v[(cth * 9 + kk) * 64 + lane];
            short8 bf_ = W1v[(ctf * 9 + kk) * 64 + lane];
            short8 a0 = *(const short8*)(smem + A1_OFF + (kk * 2 + 0) * 1024 + lane * 16);
            short8 a1 = *(const short8*)(smem + A1_OFF + (kk * 2 + 1) * 1024 + lane * 16);
            ah0 = __builtin_amdgcn_mfma_f32_16x16x32_bf16(a0, bh,  ah0, 0, 0, 0);
            ah1 = __builtin_amdgcn_mfma_f32_16x16x32_bf16(a1, bh,  ah1, 0, 0, 0);
            af0 = __builtin_amdgcn_mfma_f32_16x16x32_bf16(a0, bf_, af0, 0, 0, 0);
            af1 = __builtin_amdgcn_mfma_f32_16x16x32_bf16(a1, bf_, af1, 0, 0, 0);
        }
    }
    __syncthreads();                                        // B3: A1 dead

    // ---- h1 -> A2 fragments, FM outputs -> FMC ----
    {
        const int colh = wv * 16 + (lane & 15);
        const float bo1 = bias1f[colh];
        const int kk2 = wv >> 1;
        const int nsub = (colh & 31) >> 3;
        const int jof = (colh & 7) * 2;
        const int rbase = (lane >> 4) << 2;
        #pragma unroll
        for (int rt = 0; rt < 2; ++rt) {
            f32x4 acc = rt ? ah1 : ah0;
            #pragma unroll
            for (int r = 0; r < 4; ++r) {
                float h = fmaxf(acc[r] + bo1, 0.f);
                int r15 = rbase + r;
                *(__hip_bfloat16*)(smem + A2_OFF + (kk2 * 2 + rt) * 1024 + (r15 + 16 * nsub) * 16 + jof)
                    = __float2bfloat16(h);
            }
        }
        const int dcf = wv * 16 + (lane & 15);   // 0..63: <32 ssum, >=32 Gcont
        const int d = dcf & 31, s = dcf >> 5;
        #pragma unroll
        for (int rt = 0; rt < 2; ++rt) {
            f32x4 acc = rt ? af1 : af0;
            #pragma unroll
            for (int r = 0; r < 4; ++r) {
                int row = rt * 16 + rbase + r;
                *(float*)(smem + FMC_OFF + (row * 66 + d * 2 + s) * 4) = acc[r];
            }
        }
    }
    __syncthreads();                                        // B4

    // ---- GEMM2: (32 x 64) x (64 x 32) ----
    const int rt2 = wv >> 1, ct2 = wv & 1;
    const short8* W2v = (const short8*)W2f;
    f32x4 acc2 = {0,0,0,0};
    #pragma unroll
    for (int kk = 0; kk < 2; ++kk) {
        short8 a = *(const short8*)(smem + A2_OFF + (kk * 2 + rt2) * 1024 + lane * 16);
        short8 b = W2v[(ct2 * 2 + kk) * 64 + lane];
        acc2 = __builtin_amdgcn_mfma_f32_16x16x32_bf16(a, b, acc2, 0, 0, 0);
    }
    // h2 -> A3 fragments
    {
        const float bo2 = bias2f[ct2 * 16 + (lane & 15)];
        const int col2 = ct2 * 16 + (lane & 15);
        const int nsub2 = col2 >> 3;
        const int jof = (col2 & 7) * 2;
        const int rbase = (lane >> 4) << 2;
        #pragma unroll
        for (int r = 0; r < 4; ++r) {
            float h = fmaxf(acc2[r] + bo2, 0.f);
            *(__hip_bfloat16*)(smem + A3_OFF + rt2 * 1024 + ((rbase + r) + 16 * nsub2) * 16 + jof)
                = __float2bfloat16(h);
        }
    }
    __syncthreads();                                        // B5

    // ---- GEMM3 + epilogue ----
    {
        short8 a3 = *(const short8*)(smem + A3_OFF + rt2 * 1024 + lane * 16);
        const short8* W3v = (const short8*)W3f;
        short8 b3 = W3v[ct2 * 64 + lane];
        f32x4 z = {0,0,0,0};
        f32x4 acc3 = __builtin_amdgcn_mfma_f32_16x16x32_bf16(a3, b3, z, 0, 0, 0);

        const int dcol = ct2 * 16 + (lane & 15);
        const float ob = out_b[dcol];
        const int rbase = (lane >> 4) << 2;
        size_t outbase = (size_t)tile * 1024;
        #pragma unroll
        for (int r = 0; r < 4; ++r) {
            int p = rt2 * 16 + rbase + r;
            float2 sg = *(const float2*)(smem + FMC_OFF + (p * 66 + dcol * 2) * 4);
            float gcat = *(const float*)(smem + PART_OFF + p * 128 + dcol * 4);
            out[outbase + p * 32 + dcol] = acc3[r] + ob + gcat + sg.y + 0.5f * sg.x * sg.x;
        }
    }
}

extern "C" void kernel_launch(void* const* d_in, const int* in_sizes, int n_in,
                              void* d_out, int out_size, void* d_ws, size_t ws_size,
                              hipStream_t stream) {
    const float* x        = (const float*)d_in[0];
    const float* cat_emb  = (const float*)d_in[1];
    const float* cat_lin  = (const float*)d_in[2];
    const float* cont_w   = (const float*)d_in[3];
    const float* cont_b   = (const float*)d_in[4];
    const float* cont_lw  = (const float*)d_in[5];
    const float* cont_lb  = (const float*)d_in[6];
    const float* fin_bias = (const float*)d_in[7];
    const float* dnn1_w   = (const float*)d_in[8];
    const float* dnn1_b   = (const float*)d_in[9];
    const float* bn1_g    = (const float*)d_in[10];
    const float* bn1_bt   = (const float*)d_in[11];
    const float* bn1_m    = (const float*)d_in[12];
    const float* bn1_v    = (const float*)d_in[13];
    const float* dnn2_w   = (const float*)d_in[14];
    const float* dnn2_b   = (const float*)d_in[15];
    const float* bn2_g    = (const float*)d_in[16];
    const float* bn2_bt   = (const float*)d_in[17];
    const float* bn2_m    = (const float*)d_in[18];
    const float* bn2_v    = (const float*)d_in[19];
    const float* out_w    = (const float*)d_in[20];
    const float* out_b    = (const float*)d_in[21];

    char* ws = (char*)d_ws;
    float* bias1f = (float*)(ws + WS_B1F);
    float* bias2f = (float*)(ws + WS_B2F);
    __hip_bfloat16* W1f = (__hip_bfloat16*)(ws + WS_W1F);
    __hip_bfloat16* W2f = (__hip_bfloat16*)(ws + WS_W2F);
    __hip_bfloat16* W3f = (__hip_bfloat16*)(ws + WS_W3F);
    float2* EL = (float2*)(ws + WS_EL);

    hipLaunchKernelGGL(prep_kernel, dim3(256), dim3(BLK), 0, stream,
                       dnn1_w, dnn1_b, bn1_g, bn1_bt, bn1_m, bn1_v,
                       dnn2_w, dnn2_b, bn2_g, bn2_bt, bn2_m, bn2_v,
                       out_w, cat_emb, cat_lin, cont_w, cont_b, cont_lw, cont_lb,
                       fin_bias, bias1f, bias2f, W1f, W2f, W3f, EL);

    hipLaunchKernelGGL(fused_kernel, dim3(NTILES), dim3(BLK), 0, stream,
                       x, bias1f, bias2f, out_b, W1f, W2f, W3f, EL,
                       (float*)d_out);
}